// Round 1
// baseline (157.127 us; speedup 1.0000x reference)
//
#include <hip/hip_runtime.h>

// Shapes: B=8, C1=256, H=W=64 (HW=4096, N=32768), Ch=128, C2=256, E=4, K=2
// ws layout: W1t[256][128] | Wct[128][512] | W3t[128][256]  (= 512 KB)

__device__ __forceinline__ float silu_f(float v) {
    return v * (1.0f / (1.0f + __expf(-v)));
}

__global__ void prep_weights(const float* __restrict__ W1,
                             const float* __restrict__ We,
                             const float* __restrict__ W3,
                             float* __restrict__ W1t,
                             float* __restrict__ Wct,
                             float* __restrict__ W3t)
{
    int idx = blockIdx.x * 256 + threadIdx.x;
    if (idx < 32768) {
        // W1t[c][o] = W1[o][c], W1 is [128][256]
        int c = idx >> 7, o = idx & 127;
        W1t[idx] = W1[o * 256 + c];
    } else if (idx < 98304) {
        // Wct[c][e*128+o] = We[e][o][c][1][1], We is [4][128][128][3][3]
        int i = idx - 32768;
        int c = i >> 9, r = i & 511;
        int e = r >> 7, o = r & 127;
        Wct[i] = We[(((e * 128 + o) * 128 + c) * 9) + 4];
    } else if (idx < 131072) {
        // W3t[c][o] = W3[o][c], W3 is [256][128]
        int i = idx - 98304;
        int c = i >> 8, o = i & 255;
        W3t[i] = W3[o * 128 + c];
    }
}

// One block = 64 consecutive pixels of one batch image. Full pipeline fused.
__global__ __launch_bounds__(256, 2)
void fused_moe_kernel(const float* __restrict__ x,
                      const float* __restrict__ b1,
                      const float* __restrict__ Wr,
                      const float* __restrict__ br,
                      const float* __restrict__ be,
                      const float* __restrict__ b3,
                      const float* __restrict__ W1t,
                      const float* __restrict__ Wct,
                      const float* __restrict__ W3t,
                      float* __restrict__ out)
{
    __shared__ __align__(16) float sA[32 * 64];    //  8 KB: x k-chunk [32][64]
    __shared__ __align__(16) float sW[32 * 256];   // 32 KB: weight chunk (union)
    __shared__ __align__(16) float sX[128 * 68];   // 34 KB: x_in / moe tile, [128][68]
    __shared__ float sR[4 * 64];                   //  1 KB: router weights [e][m]
    __shared__ __align__(16) float sWr[512];       //  2 KB: router matrix

    const int tid = threadIdx.x;
    const int tm = tid >> 4;   // 0..15 -> pixel group (4 pixels each)
    const int tn = tid & 15;   // 0..15 -> channel lane (strided by 16)
    const int tile = blockIdx.x;          // 0..511
    const int n0   = tile << 6;
    const int b    = n0 >> 12;
    const int hw0  = n0 & 4095;
    const float* xb = x + ((size_t)b * 256) * 4096 + hw0;

    // ===================== GEMM1: silu(X @ W1^T + b1) =====================
    float acc[4][8];
#pragma unroll
    for (int i = 0; i < 4; i++)
#pragma unroll
        for (int j = 0; j < 8; j++) acc[i][j] = 0.f;

#pragma unroll 1
    for (int c0 = 0; c0 < 256; c0 += 32) {
        __syncthreads();
#pragma unroll
        for (int q = 0; q < 2; q++) {               // x chunk [32][64]
            int idx = tid + q * 256;
            int c = idx >> 4, m4 = (idx & 15) << 2;
            *(float4*)&sA[c * 64 + m4] =
                *(const float4*)&xb[(size_t)(c0 + c) * 4096 + m4];
        }
#pragma unroll
        for (int q = 0; q < 4; q++) {               // W1t chunk [32][128]
            int idx = tid + q * 256;
            int c = idx >> 5, o4 = (idx & 31) << 2;
            *(float4*)&sW[c * 128 + o4] =
                *(const float4*)&W1t[(size_t)(c0 + c) * 128 + o4];
        }
        __syncthreads();
#pragma unroll 8
        for (int kk = 0; kk < 32; kk++) {
            float4 a = *(float4*)&sA[kk * 64 + tm * 4];
            float w[8];
#pragma unroll
            for (int j = 0; j < 8; j++) w[j] = sW[kk * 128 + tn + j * 16];
#pragma unroll
            for (int j = 0; j < 8; j++) {
                acc[0][j] += a.x * w[j];
                acc[1][j] += a.y * w[j];
                acc[2][j] += a.z * w[j];
                acc[3][j] += a.w * w[j];
            }
        }
    }
    // preload router weights while epilogue runs
    if (tid < 128)
        *(float4*)&sWr[tid * 4] = *(const float4*)&Wr[tid * 4];
    // epilogue: bias + silu -> sX[c][m]
#pragma unroll
    for (int j = 0; j < 8; j++) {
        int o = tn + j * 16;
        float bb = b1[o];
#pragma unroll
        for (int i = 0; i < 4; i++) {
            float v = acc[i][j] + bb;
            sX[o * 68 + tm * 4 + i] = silu_f(v);
        }
    }
    __syncthreads();

    // ===================== Router: softmax + top-2 =====================
    if (tid < 64) {
        float lg[4] = {br[0], br[1], br[2], br[3]};
        for (int c = 0; c < 128; c++) {
            float v = sX[c * 68 + tid];
#pragma unroll
            for (int e = 0; e < 4; e++) lg[e] += v * sWr[e * 128 + c];
        }
        int i1 = 0;
#pragma unroll
        for (int e = 1; e < 4; e++) if (lg[e] > lg[i1]) i1 = e;
        int i2 = (i1 == 0) ? 1 : 0;
#pragma unroll
        for (int e = 0; e < 4; e++) if (e != i1 && lg[e] > lg[i2]) i2 = e;
        float e2  = __expf(lg[i2] - lg[i1]);
        float inv = 1.0f / (1.0f + e2);
#pragma unroll
        for (int e = 0; e < 4; e++)
            sR[e * 64 + tid] = (e == i1) ? inv : (e == i2) ? e2 * inv : 0.f;
    }
    // (expert-loop leading __syncthreads() covers sR/sX hazards)

    // ===================== Experts: dense 4x, weighted accumulate =====================
    float accm[4][8];
#pragma unroll
    for (int i = 0; i < 4; i++)
#pragma unroll
        for (int j = 0; j < 8; j++) accm[i][j] = 0.f;

#pragma unroll 1
    for (int e = 0; e < 4; e++) {
        float acce[4][8];
#pragma unroll
        for (int i = 0; i < 4; i++)
#pragma unroll
            for (int j = 0; j < 8; j++) acce[i][j] = 0.f;
#pragma unroll 1
        for (int c0 = 0; c0 < 128; c0 += 32) {
            __syncthreads();
#pragma unroll
            for (int q = 0; q < 4; q++) {          // Wct chunk [32][128] for expert e
                int idx = tid + q * 256;
                int c = idx >> 5, o4 = (idx & 31) << 2;
                *(float4*)&sW[c * 128 + o4] =
                    *(const float4*)&Wct[(size_t)(c0 + c) * 512 + e * 128 + o4];
            }
            __syncthreads();
#pragma unroll 8
            for (int kk = 0; kk < 32; kk++) {
                float4 a = *(float4*)&sX[(c0 + kk) * 68 + tm * 4];
                float w[8];
#pragma unroll
                for (int j = 0; j < 8; j++) w[j] = sW[kk * 128 + tn + j * 16];
#pragma unroll
                for (int j = 0; j < 8; j++) {
                    acce[0][j] += a.x * w[j];
                    acce[1][j] += a.y * w[j];
                    acce[2][j] += a.z * w[j];
                    acce[3][j] += a.w * w[j];
                }
            }
        }
#pragma unroll
        for (int j = 0; j < 8; j++) {
            int o = tn + j * 16;
            float bb = be[e * 128 + o];
#pragma unroll
            for (int i = 0; i < 4; i++) {
                float wgt = sR[e * 64 + tm * 4 + i];
                accm[i][j] += wgt * silu_f(acce[i][j] + bb);
            }
        }
    }

    // write moe back into sX (reuse)
    __syncthreads();
#pragma unroll
    for (int j = 0; j < 8; j++) {
        int o = tn + j * 16;
#pragma unroll
        for (int i = 0; i < 4; i++) sX[o * 68 + tm * 4 + i] = accm[i][j];
    }
    __syncthreads();

    // ===================== GEMM3: silu(moe @ W3^T + b3) + x =====================
    float acc3[4][16];
#pragma unroll
    for (int i = 0; i < 4; i++)
#pragma unroll
        for (int j = 0; j < 16; j++) acc3[i][j] = 0.f;

#pragma unroll 1
    for (int c0 = 0; c0 < 128; c0 += 32) {
        __syncthreads();
#pragma unroll
        for (int q = 0; q < 8; q++) {              // W3t chunk [32][256]
            int idx = tid + q * 256;
            int c = idx >> 6, o4 = (idx & 63) << 2;
            *(float4*)&sW[c * 256 + o4] =
                *(const float4*)&W3t[(size_t)(c0 + c) * 256 + o4];
        }
        __syncthreads();
#pragma unroll 4
        for (int kk = 0; kk < 32; kk++) {
            float4 a = *(float4*)&sX[(c0 + kk) * 68 + tm * 4];
            float w[16];
#pragma unroll
            for (int j = 0; j < 16; j++) w[j] = sW[kk * 256 + tn + j * 16];
#pragma unroll
            for (int j = 0; j < 16; j++) {
                acc3[0][j] += a.x * w[j];
                acc3[1][j] += a.y * w[j];
                acc3[2][j] += a.z * w[j];
                acc3[3][j] += a.w * w[j];
            }
        }
    }

    float* yb = out + ((size_t)b * 256) * 4096 + hw0;
#pragma unroll
    for (int j = 0; j < 16; j++) {
        int o = tn + j * 16;
        float bb = b3[o];
        float4 r = *(const float4*)&xb[(size_t)o * 4096 + tm * 4];
        float4 v;
        v.x = silu_f(acc3[0][j] + bb) + r.x;
        v.y = silu_f(acc3[1][j] + bb) + r.y;
        v.z = silu_f(acc3[2][j] + bb) + r.z;
        v.w = silu_f(acc3[3][j] + bb) + r.w;
        *(float4*)&yb[(size_t)o * 4096 + tm * 4] = v;
    }
}

extern "C" void kernel_launch(void* const* d_in, const int* in_sizes, int n_in,
                              void* d_out, int out_size, void* d_ws, size_t ws_size,
                              hipStream_t stream)
{
    const float* x  = (const float*)d_in[0];
    const float* W1 = (const float*)d_in[1];
    const float* b1 = (const float*)d_in[2];
    const float* Wr = (const float*)d_in[3];
    const float* br = (const float*)d_in[4];
    const float* We = (const float*)d_in[5];
    const float* be = (const float*)d_in[6];
    const float* W3 = (const float*)d_in[7];
    const float* b3 = (const float*)d_in[8];
    float* outp = (float*)d_out;

    float* W1t = (float*)d_ws;        // 32768 floats
    float* Wct = W1t + 32768;         // 65536 floats
    float* W3t = Wct + 65536;         // 32768 floats

    hipLaunchKernelGGL(prep_weights, dim3(512), dim3(256), 0, stream,
                       W1, We, W3, W1t, Wct, W3t);
    hipLaunchKernelGGL(fused_moe_kernel, dim3(512), dim3(256), 0, stream,
                       x, b1, Wr, br, be, b3, W1t, Wct, W3t, outp);
}

// Round 3
// 65.488 us; speedup vs baseline: 2.3993x; 2.3993x over previous
//
#include <hip/hip_runtime.h>

// B=8, C1=256, HW=4096 (N=32768), Ch=128, C2=256, E=4, K=2
// ws layout (ushorts):
//   W1hi [kc=4][128][72] @0        (36864)
//   W1lo [kc=4][128][72] @36864    (36864)
//   Wec  [e=4][128][136] @73728    (69632)
//   W3c  [h=2][128][136] @143360   (34816)
// total 178176 ushorts = 356352 B

typedef unsigned short ushort_t;
typedef unsigned int uint_t;
typedef __attribute__((ext_vector_type(8))) short short8;
typedef __attribute__((ext_vector_type(4))) float f32x4;

#define MFMA16 __builtin_amdgcn_mfma_f32_16x16x32_bf16

__device__ __forceinline__ float silu_f(float v) { return v / (1.0f + __expf(-v)); }
__device__ __forceinline__ ushort_t f2bf(float f) {
    uint_t u = __float_as_uint(f);
    return (ushort_t)((u + 0x7fff + ((u >> 16) & 1)) >> 16);
}
__device__ __forceinline__ float bf2f(ushort_t h) { return __uint_as_float(((uint_t)h) << 16); }

__global__ void prep_weights(const float* __restrict__ W1,
                             const float* __restrict__ We,
                             const float* __restrict__ W3,
                             ushort_t* __restrict__ ws)
{
    int idx = blockIdx.x * 256 + threadIdx.x;
    if (idx < 36864) {                       // W1 hi+lo, K-chunks of 64, stride 72
        int kc = idx / 9216, r = idx % 9216;
        int n = r / 72, j = r % 72;
        float v = (j < 64) ? W1[n * 256 + kc * 64 + j] : 0.0f;
        ushort_t h = f2bf(v);
        float lo = v - bf2f(h);
        ws[idx] = h;
        ws[36864 + idx] = f2bf(lo);
    } else if (idx < 106496) {               // We center taps [e][n][136]
        int i = idx - 36864;
        int e = i / 17408, r = i % 17408;
        int n = r / 136, j = r % 136;
        ws[73728 + i] = (j < 128)
            ? f2bf(We[(size_t)(((e * 128 + n) * 128 + j) * 9) + 4]) : (ushort_t)0;
    } else if (idx < 141312) {               // W3 halves [h][n][136]
        int i = idx - 106496;
        int h = i / 17408, r = i % 17408;
        int n = r / 136, j = r % 136;
        ws[143360 + i] = (j < 128)
            ? f2bf(W3[(size_t)(h * 128 + n) * 128 + j]) : (ushort_t)0;
    }
}

// One block = 64 consecutive pixels. 4 waves. Full pipeline fused.
// GEMM1: 4-pass split-bf16 (fp32-quality) -> router decisions stable.
__global__ __launch_bounds__(256, 2)
void fused_moe_mfma(const float* __restrict__ x,
                    const float* __restrict__ b1,
                    const float* __restrict__ Wr,
                    const float* __restrict__ br,
                    const float* __restrict__ be,
                    const float* __restrict__ b3,
                    const ushort_t* __restrict__ wbf,
                    float* __restrict__ out)
{
    __shared__ __align__(16) unsigned char smem[71680];
    ushort_t* sWhi = (ushort_t*)(smem);            // P1: [128][72] = 18432 B
    ushort_t* sWlo = (ushort_t*)(smem + 18432);    //     [128][72]
    ushort_t* sAhi = (ushort_t*)(smem + 36864);    //     [64][72] = 9216 B
    ushort_t* sAlo = (ushort_t*)(smem + 46080);    //     ends 55296
    ushort_t* sA2  = (ushort_t*)(smem);            // P2+: [64][136] = 17408 B
    ushort_t* sWe  = (ushort_t*)(smem + 17408);    //     [128][136] = 34816 B
    ushort_t* sA3  = (ushort_t*)(smem + 52224);    //     [64][136], ends 69632
    ushort_t* sW3  = (ushort_t*)(smem + 17408);    // P4: [128][136]
    float*    sY   = (float*)(smem);               //     [128][68] = 34816 B
    float*    sWr  = (float*)(smem + 69632);       // 2048 B

    const int tid = threadIdx.x;
    const int l  = tid & 63;
    const int w  = tid >> 6;
    const int lr = l & 15;
    const int g  = l >> 4;
    const int lk = g * 8;
    const int mrow = 16 * w + 4 * g;

    const int n0  = blockIdx.x << 6;
    const int bi  = n0 >> 12;
    const int hw0 = n0 & 4095;
    const float* xb = x   + (size_t)bi * 256 * 4096 + hw0;
    float*       ob = out + (size_t)bi * 256 * 4096 + hw0;

    if (tid < 128) *(float4*)&sWr[tid * 4] = *(const float4*)&Wr[tid * 4];

    // ============ GEMM1: x @ W1^T, split-bf16 4-pass ============
    f32x4 acc1[8];
#pragma unroll
    for (int f = 0; f < 8; ++f) acc1[f] = (f32x4){0.f, 0.f, 0.f, 0.f};

    uint_t* aHi32 = (uint_t*)sAhi;
    uint_t* aLo32 = (uint_t*)sAlo;

#pragma unroll 1
    for (int kc = 0; kc < 4; ++kc) {
        __syncthreads();
#pragma unroll
        for (int q = 0; q < 5; ++q) {              // W1 chunk hi+lo: 1152 x 16B each
            int idx = q * 256 + tid;
            if (idx < 1152) {
                *(short8*)&sWhi[idx * 8] = *(const short8*)&wbf[kc * 9216 + idx * 8];
                *(short8*)&sWlo[idx * 8] = *(const short8*)&wbf[36864 + kc * 9216 + idx * 8];
            }
        }
#pragma unroll
        for (int q = 0; q < 2; ++q) {              // A chunk: 64ch x 64px, hi+lo
            int idx = q * 256 + tid;
            int c2 = idx >> 4, m4 = (idx & 15) << 2;
            int c = kc * 64 + c2 * 2;
            float4 fa = *(const float4*)&xb[(size_t)c * 4096 + m4];
            float4 fb = *(const float4*)&xb[(size_t)(c + 1) * 4096 + m4];
            float fav[4] = {fa.x, fa.y, fa.z, fa.w};
            float fbv[4] = {fb.x, fb.y, fb.z, fb.w};
#pragma unroll
            for (int r = 0; r < 4; ++r) {
                ushort_t ha = f2bf(fav[r]), hb = f2bf(fbv[r]);
                float la = fav[r] - bf2f(ha), lb = fbv[r] - bf2f(hb);
                aHi32[(m4 + r) * 36 + c2] = (uint_t)ha | ((uint_t)hb << 16);
                aLo32[(m4 + r) * 36 + c2] = (uint_t)f2bf(la) | ((uint_t)f2bf(lb) << 16);
            }
        }
        __syncthreads();
#pragma unroll
        for (int ks = 0; ks < 2; ++ks) {
            short8 ah = *(const short8*)&sAhi[(16 * w + lr) * 72 + ks * 32 + lk];
            short8 al = *(const short8*)&sAlo[(16 * w + lr) * 72 + ks * 32 + lk];
#pragma unroll
            for (int f = 0; f < 8; ++f) {
                short8 bh = *(const short8*)&sWhi[(16 * f + lr) * 72 + ks * 32 + lk];
                short8 bl = *(const short8*)&sWlo[(16 * f + lr) * 72 + ks * 32 + lk];
                acc1[f] = MFMA16(ah, bh, acc1[f], 0, 0, 0);
                acc1[f] = MFMA16(al, bh, acc1[f], 0, 0, 0);
                acc1[f] = MFMA16(ah, bl, acc1[f], 0, 0, 0);
                acc1[f] = MFMA16(al, bl, acc1[f], 0, 0, 0);
            }
        }
    }
    __syncthreads();                               // GEMM1 LDS reads done

    // ============ epilogue: xin fp32 in regs; A2 bf16; router fp32 ============
    float xin[8][4];
#pragma unroll
    for (int f = 0; f < 8; ++f) {
        float bias = b1[16 * f + lr];
#pragma unroll
        for (int i = 0; i < 4; ++i) xin[f][i] = silu_f(acc1[f][i] + bias);
    }
#pragma unroll
    for (int f = 0; f < 8; ++f) {
        int c = 16 * f + lr;
#pragma unroll
        for (int i = 0; i < 4; ++i)
            sA2[(mrow + i) * 136 + c] = f2bf(xin[f][i]);
    }

    float lg[4][4];
#pragma unroll
    for (int e = 0; e < 4; ++e)
#pragma unroll
        for (int i = 0; i < 4; ++i) lg[e][i] = 0.f;
#pragma unroll
    for (int f = 0; f < 8; ++f) {
        int c = 16 * f + lr;
        float w0 = sWr[c], w1 = sWr[128 + c], w2 = sWr[256 + c], w3 = sWr[384 + c];
#pragma unroll
        for (int i = 0; i < 4; ++i) {
            float xv = xin[f][i];
            lg[0][i] += xv * w0; lg[1][i] += xv * w1;
            lg[2][i] += xv * w2; lg[3][i] += xv * w3;
        }
    }
#pragma unroll
    for (int d = 1; d < 16; d <<= 1)
#pragma unroll
        for (int e = 0; e < 4; ++e)
#pragma unroll
            for (int i = 0; i < 4; ++i)
                lg[e][i] += __shfl_xor(lg[e][i], d, 64);

    float br0 = br[0], br1 = br[1], br2 = br[2], br3 = br[3];
    float rw[4][4];
#pragma unroll
    for (int i = 0; i < 4; ++i) {
        float le0 = lg[0][i] + br0, le1 = lg[1][i] + br1;
        float le2 = lg[2][i] + br2, le3 = lg[3][i] + br3;
        // rank counts (tie-break: earlier index wins, matching top_k)
        int c0 = (le1 > le0) + (le2 > le0) + (le3 > le0);
        int c1 = (le0 >= le1) + (le2 > le1) + (le3 > le1);
        int c2 = (le0 >= le2) + (le1 >= le2) + (le3 > le2);
        int c3 = (le0 >= le3) + (le1 >= le3) + (le2 >= le3);
        float m = fmaxf(fmaxf(le0, le1), fmaxf(le2, le3));
        float p0 = (c0 < 2) ? __expf(le0 - m) : 0.f;
        float p1 = (c1 < 2) ? __expf(le1 - m) : 0.f;
        float p2 = (c2 < 2) ? __expf(le2 - m) : 0.f;
        float p3 = (c3 < 2) ? __expf(le3 - m) : 0.f;
        float inv = 1.0f / (p0 + p1 + p2 + p3);
        rw[0][i] = p0 * inv; rw[1][i] = p1 * inv;
        rw[2][i] = p2 * inv; rw[3][i] = p3 * inv;
    }

    // ============ Experts: dense 4x bf16 MFMA, weighted accumulate ============
    f32x4 macc[8];
#pragma unroll
    for (int f = 0; f < 8; ++f) macc[f] = (f32x4){0.f, 0.f, 0.f, 0.f};

#pragma unroll
    for (int e = 0; e < 4; ++e) {
        __syncthreads();
#pragma unroll
        for (int q = 0; q < 9; ++q) {
            int idx = q * 256 + tid;
            if (idx < 2176)
                *(short8*)&sWe[idx * 8] =
                    *(const short8*)&wbf[73728 + e * 17408 + idx * 8];
        }
        __syncthreads();
        f32x4 acce[8];
#pragma unroll
        for (int f = 0; f < 8; ++f) acce[f] = (f32x4){0.f, 0.f, 0.f, 0.f};
#pragma unroll
        for (int ks = 0; ks < 4; ++ks) {
            short8 a = *(const short8*)&sA2[(16 * w + lr) * 136 + ks * 32 + lk];
#pragma unroll
            for (int f = 0; f < 8; ++f) {
                short8 bb = *(const short8*)&sWe[(16 * f + lr) * 136 + ks * 32 + lk];
                acce[f] = MFMA16(a, bb, acce[f], 0, 0, 0);
            }
        }
#pragma unroll
        for (int f = 0; f < 8; ++f) {
            float bias = be[e * 128 + 16 * f + lr];
#pragma unroll
            for (int i = 0; i < 4; ++i)
                macc[f][i] += rw[e][i] * silu_f(acce[f][i] + bias);
        }
    }
    // moe -> A3 (region untouched since GEMM1; disjoint from sA2/sWe)
#pragma unroll
    for (int f = 0; f < 8; ++f) {
        int c = 16 * f + lr;
#pragma unroll
        for (int i = 0; i < 4; ++i)
            sA3[(mrow + i) * 136 + c] = f2bf(macc[f][i]);
    }

    // ============ GEMM3: silu(moe @ W3^T + b3) + x ============
#pragma unroll 1
    for (int h = 0; h < 2; ++h) {
        __syncthreads();                           // A3 writes + prior reads done
#pragma unroll
        for (int q = 0; q < 9; ++q) {
            int idx = q * 256 + tid;
            if (idx < 2176)
                *(short8*)&sW3[idx * 8] =
                    *(const short8*)&wbf[143360 + h * 17408 + idx * 8];
        }
        __syncthreads();
        f32x4 acc3[8];
#pragma unroll
        for (int f = 0; f < 8; ++f) acc3[f] = (f32x4){0.f, 0.f, 0.f, 0.f};
#pragma unroll
        for (int ks = 0; ks < 4; ++ks) {
            short8 a = *(const short8*)&sA3[(16 * w + lr) * 136 + ks * 32 + lk];
#pragma unroll
            for (int f = 0; f < 8; ++f) {
                short8 bb = *(const short8*)&sW3[(16 * f + lr) * 136 + ks * 32 + lk];
                acc3[f] = MFMA16(a, bb, acc3[f], 0, 0, 0);
            }
        }
        __syncthreads();                           // W3/A3 reads done; sY may clobber
#pragma unroll
        for (int f = 0; f < 8; ++f) {
            int o = 16 * f + lr;
            float bias = b3[h * 128 + o];
#pragma unroll
            for (int i = 0; i < 4; ++i)
                sY[o * 68 + mrow + i] = silu_f(acc3[f][i] + bias);
        }
        __syncthreads();
#pragma unroll
        for (int q = 0; q < 8; ++q) {              // coalesced residual-add + store
            int idx = q * 256 + tid;
            int o = idx >> 4, m4 = (idx & 15) << 2;
            int og = h * 128 + o;
            float4 vy = *(float4*)&sY[o * 68 + m4];
            float4 r  = *(const float4*)&xb[(size_t)og * 4096 + m4];
            vy.x += r.x; vy.y += r.y; vy.z += r.z; vy.w += r.w;
            *(float4*)&ob[(size_t)og * 4096 + m4] = vy;
        }
    }
}

extern "C" void kernel_launch(void* const* d_in, const int* in_sizes, int n_in,
                              void* d_out, int out_size, void* d_ws, size_t ws_size,
                              hipStream_t stream)
{
    const float* x  = (const float*)d_in[0];
    const float* W1 = (const float*)d_in[1];
    const float* b1 = (const float*)d_in[2];
    const float* Wr = (const float*)d_in[3];
    const float* br = (const float*)d_in[4];
    const float* We = (const float*)d_in[5];
    const float* be = (const float*)d_in[6];
    const float* W3 = (const float*)d_in[7];
    const float* b3 = (const float*)d_in[8];
    float* outp = (float*)d_out;
    ushort_t* wbf = (ushort_t*)d_ws;

    hipLaunchKernelGGL(prep_weights, dim3(552), dim3(256), 0, stream,
                       W1, We, W3, wbf);
    hipLaunchKernelGGL(fused_moe_mfma, dim3(512), dim3(256), 0, stream,
                       x, b1, Wr, br, be, b3, wbf, outp);
}

// Round 8
// 57.873 us; speedup vs baseline: 2.7150x; 1.1316x over previous
//
#include <hip/hip_runtime.h>
#include <hip/hip_bf16.h>

// B=8, C1=256, HW=4096 (N=32768), Ch=128, C2=256, E=4, K=2
// ws layout (u16) — IDENTICAL to the round-3 PASSING kernel:
//   W1hi [kc=4][128][72] @0        (36864)
//   W1lo [kc=4][128][72] @36864    (36864)
//   Wec  [e=4][128][136] @73728    (69632)
//   W3c  [h=2][128][136] @143360   (34816)

typedef unsigned short u16;
typedef unsigned int   u32;
typedef __attribute__((ext_vector_type(8))) short short8;
typedef __attribute__((ext_vector_type(4))) float f32x4;

#define MFMA16 __builtin_amdgcn_mfma_f32_16x16x32_bf16

__device__ __forceinline__ float silu_f(float v) { return v / (1.0f + __expf(-v)); }
__device__ __forceinline__ u16 f2bf(float f) {
    u32 u = __float_as_uint(f);
    return (u16)((u + 0x7fff + ((u >> 16) & 1)) >> 16);
}
__device__ __forceinline__ float bf2f(u16 h) { return __uint_as_float(((u32)h) << 16); }
__device__ __forceinline__ u32 pkbf(float a, float b) {
    __hip_bfloat162 h2 = __float22bfloat162_rn(make_float2(a, b));
    u32 r; __builtin_memcpy(&r, &h2, 4); return r;
}

__global__ void prep_weights(const float* __restrict__ W1,
                             const float* __restrict__ We,
                             const float* __restrict__ W3,
                             u16* __restrict__ ws)
{
    int idx = blockIdx.x * 256 + threadIdx.x;
    if (idx < 36864) {                       // W1 hi+lo, K-chunks of 64, stride 72
        int kc = idx / 9216, r = idx % 9216;
        int n = r / 72, j = r % 72;
        float v = (j < 64) ? W1[n * 256 + kc * 64 + j] : 0.0f;
        u16 h = f2bf(v);
        float lo = v - bf2f(h);
        ws[idx] = h;
        ws[36864 + idx] = f2bf(lo);
    } else if (idx < 106496) {               // We center taps [e][n][136]
        int i = idx - 36864;
        int e = i / 17408, r = i % 17408;
        int n = r / 136, j = r % 136;
        ws[73728 + i] = (j < 128)
            ? f2bf(We[(size_t)(((e * 128 + n) * 128 + j) * 9) + 4]) : (u16)0;
    } else if (idx < 141312) {               // W3 halves [h][n][136]
        int i = idx - 106496;
        int h = i / 17408, r = i % 17408;
        int n = r / 136, j = r % 136;
        ws[143360 + i] = (j < 128)
            ? f2bf(W3[(size_t)(h * 128 + n) * 128 + j]) : (u16)0;
    }
}

// Linear 16B-per-lane DMA: unit idx = i*256+tid, LDS gets an exact linear copy.
// (global_load_lds LDS dest = wave-uniform base + lane*16B; base uses tid&192.)
__device__ __forceinline__ void dma_u16(const u16* __restrict__ g, u16* l, int i, int tid) {
    int idx = i * 256 + tid;
    int ub  = i * 256 + (tid & 192);
    __builtin_amdgcn_global_load_lds(g + (size_t)idx * 8, l + ub * 8, 16, 0, 0);
}

// One block = 64 consecutive pixels. 4 waves. Bit-identical compute to the
// round-3 PASSING kernel; only the weight staging is DMA'd.
__global__ __launch_bounds__(256, 2)
void fused_moe_mfma(const float* __restrict__ x,
                    const float* __restrict__ b1,
                    const float* __restrict__ Wr,
                    const float* __restrict__ br,
                    const float* __restrict__ be,
                    const float* __restrict__ b3,
                    const u16* __restrict__ wbf,
                    float* __restrict__ out)
{
    __shared__ __align__(16) unsigned char smem[71680];
    u16*   const sWhi = (u16*)(smem);             // P1: [128][72] = 18432 B
    u16*   const sWlo = (u16*)(smem + 18432);
    u16*   const sAhi = (u16*)(smem + 36864);     //     [64][72] = 9216 B
    u16*   const sAlo = (u16*)(smem + 46080);     //     ends 55296
    u16*   const sA2  = (u16*)(smem);             // P2+: [64][136] = 17408 B
    u16*   const sWe  = (u16*)(smem + 17408);     //     [128][136] = 34816 B
    u16*   const sA3  = (u16*)(smem + 52224);     //     [64][136], ends 69632
    u16*   const sW3  = (u16*)(smem + 17408);     // P3: [128][136]
    float* const sY   = (float*)(smem);           //     [128][68] fp32
    float* const sWr  = (float*)(smem + 69632);   // 2048 B

    const int tid = threadIdx.x;
    const int l  = tid & 63;
    const int w  = tid >> 6;
    const int lr = l & 15;
    const int g  = l >> 4;
    const int lk = g * 8;
    const int mrow = 16 * w + 4 * g;

    const int n0  = blockIdx.x << 6;
    const float* xb = x   + ((size_t)(n0 >> 12) * 256) * 4096 + (n0 & 4095);
    float*       ob = out + ((size_t)(n0 >> 12) * 256) * 4096 + (n0 & 4095);

    if (tid < 128) *(float4*)&sWr[tid * 4] = *(const float4*)&Wr[tid * 4];

    // ============ GEMM1: x @ W1^T, split-bf16 4-pass ============
    f32x4 acc1[8];
#pragma unroll
    for (int f = 0; f < 8; ++f) acc1[f] = (f32x4){0.f, 0.f, 0.f, 0.f};

    const int c2a = tid >> 4;            // channel-pair 0..15
    const int c2b = 16 + c2a;            // channel-pair 16..31
    const int m4  = (tid & 15) << 2;     // pixel row base

#pragma unroll 1
    for (int kc = 0; kc < 4; ++kc) {
        __syncthreads();
        // x loads first (older than the DMAs -> conversion doesn't drain them)
        const float* xa0 = xb + (size_t)(kc * 64 + 2 * c2a) * 4096 + m4;
        const float* xa1 = xb + (size_t)(kc * 64 + 2 * c2b) * 4096 + m4;
        float4 fa0 = *(const float4*)xa0;
        float4 fb0 = *(const float4*)(xa0 + 4096);
        float4 fa1 = *(const float4*)xa1;
        float4 fb1 = *(const float4*)(xa1 + 4096);
        // DMA W1 chunk kc: hi + lo, 1152 16B-units each (whole-wave guarded)
#pragma unroll
        for (int i = 0; i < 5; ++i) {
            if (i * 256 + tid < 1152) {
                dma_u16(wbf + (size_t)kc * 9216,           sWhi, i, tid);
                dma_u16(wbf + (size_t)(36864 + kc * 9216), sWlo, i, tid);
            }
        }
        // split conversion -> sAhi/sAlo [64 px][64 ch], u32 stride 36
        u32* H = (u32*)sAhi; u32* L = (u32*)sAlo;
        {
            float fav[4] = {fa0.x, fa0.y, fa0.z, fa0.w};
            float fbv[4] = {fb0.x, fb0.y, fb0.z, fb0.w};
#pragma unroll
            for (int r = 0; r < 4; ++r) {
                int ui = (m4 + r) * 36 + c2a;
                u32 hi = pkbf(fav[r], fbv[r]);
                float la = fav[r] - __uint_as_float(hi << 16);
                float lb = fbv[r] - __uint_as_float(hi & 0xffff0000u);
                H[ui] = hi; L[ui] = pkbf(la, lb);
            }
        }
        {
            float fav[4] = {fa1.x, fa1.y, fa1.z, fa1.w};
            float fbv[4] = {fb1.x, fb1.y, fb1.z, fb1.w};
#pragma unroll
            for (int r = 0; r < 4; ++r) {
                int ui = (m4 + r) * 36 + c2b;
                u32 hi = pkbf(fav[r], fbv[r]);
                float la = fav[r] - __uint_as_float(hi << 16);
                float lb = fbv[r] - __uint_as_float(hi & 0xffff0000u);
                H[ui] = hi; L[ui] = pkbf(la, lb);
            }
        }
        __syncthreads();                 // drains DMA (vmcnt) + LDS writes
        // 4-pass MFMA
#pragma unroll
        for (int ks = 0; ks < 2; ++ks) {
            short8 ah = *(const short8*)&sAhi[(16 * w + lr) * 72 + ks * 32 + lk];
            short8 al = *(const short8*)&sAlo[(16 * w + lr) * 72 + ks * 32 + lk];
#pragma unroll
            for (int f = 0; f < 8; ++f) {
                int bo = (16 * f + lr) * 72 + ks * 32 + lk;
                short8 bh = *(const short8*)&sWhi[bo];
                short8 bl = *(const short8*)&sWlo[bo];
                acc1[f] = MFMA16(ah, bh, acc1[f], 0, 0, 0);
                acc1[f] = MFMA16(al, bh, acc1[f], 0, 0, 0);
                acc1[f] = MFMA16(ah, bl, acc1[f], 0, 0, 0);
                acc1[f] = MFMA16(al, bl, acc1[f], 0, 0, 0);
            }
        }
    }
    __syncthreads();                     // P1 LDS reads done; sA2 may overwrite

    // ============ epilogue: xin fp32 in regs; A2 bf16; fp32 router ============
    float xin[8][4];
#pragma unroll
    for (int f = 0; f < 8; ++f) {
        float bias = b1[16 * f + lr];
#pragma unroll
        for (int i = 0; i < 4; ++i) xin[f][i] = silu_f(acc1[f][i] + bias);
    }
#pragma unroll
    for (int f = 0; f < 8; ++f) {
        int c = 16 * f + lr;
#pragma unroll
        for (int i = 0; i < 4; ++i)
            sA2[(mrow + i) * 136 + c] = f2bf(xin[f][i]);
    }

    float lg[4][4];
#pragma unroll
    for (int e = 0; e < 4; ++e)
#pragma unroll
        for (int i = 0; i < 4; ++i) lg[e][i] = 0.f;
#pragma unroll
    for (int f = 0; f < 8; ++f) {
        int c = 16 * f + lr;
        float w0 = sWr[c], w1 = sWr[128 + c], w2 = sWr[256 + c], w3 = sWr[384 + c];
#pragma unroll
        for (int i = 0; i < 4; ++i) {
            float xv = xin[f][i];
            lg[0][i] += xv * w0; lg[1][i] += xv * w1;
            lg[2][i] += xv * w2; lg[3][i] += xv * w3;
        }
    }
#pragma unroll
    for (int d = 1; d < 16; d <<= 1)
#pragma unroll
        for (int e = 0; e < 4; ++e)
#pragma unroll
            for (int i = 0; i < 4; ++i)
                lg[e][i] += __shfl_xor(lg[e][i], d, 64);

    float br0 = br[0], br1 = br[1], br2 = br[2], br3 = br[3];
    float rw[4][4];
#pragma unroll
    for (int i = 0; i < 4; ++i) {
        float le0 = lg[0][i] + br0, le1 = lg[1][i] + br1;
        float le2 = lg[2][i] + br2, le3 = lg[3][i] + br3;
        // rank counts (tie-break: earlier index wins, matching top_k)
        int c0 = (le1 > le0) + (le2 > le0) + (le3 > le0);
        int c1 = (le0 >= le1) + (le2 > le1) + (le3 > le1);
        int c2 = (le0 >= le2) + (le1 >= le2) + (le3 > le2);
        int c3 = (le0 >= le3) + (le1 >= le3) + (le2 >= le3);
        float m = fmaxf(fmaxf(le0, le1), fmaxf(le2, le3));
        float p0 = (c0 < 2) ? __expf(le0 - m) : 0.f;
        float p1 = (c1 < 2) ? __expf(le1 - m) : 0.f;
        float p2 = (c2 < 2) ? __expf(le2 - m) : 0.f;
        float p3 = (c3 < 2) ? __expf(le3 - m) : 0.f;
        float inv = 1.0f / (p0 + p1 + p2 + p3);
        rw[0][i] = p0 * inv; rw[1][i] = p1 * inv;
        rw[2][i] = p2 * inv; rw[3][i] = p3 * inv;
    }

    // ============ Experts: dense 4x bf16 MFMA, weighted accumulate ============
    f32x4 macc[8];
#pragma unroll
    for (int f = 0; f < 8; ++f) macc[f] = (f32x4){0.f, 0.f, 0.f, 0.f};

#pragma unroll 1
    for (int e = 0; e < 4; ++e) {
        __syncthreads();                 // prior chunk's readers done
#pragma unroll
        for (int i9 = 0; i9 < 9; ++i9)
            if (i9 * 256 + tid < 2176)
                dma_u16(wbf + (size_t)(73728 + e * 17408), sWe, i9, tid);
        __syncthreads();                 // DMA drained; A2 writes visible
        f32x4 acce[8];
#pragma unroll
        for (int f = 0; f < 8; ++f) acce[f] = (f32x4){0.f, 0.f, 0.f, 0.f};
#pragma unroll
        for (int ks = 0; ks < 4; ++ks) {
            short8 a = *(const short8*)&sA2[(16 * w + lr) * 136 + ks * 32 + lk];
#pragma unroll
            for (int f = 0; f < 8; ++f) {
                short8 bb = *(const short8*)&sWe[(16 * f + lr) * 136 + ks * 32 + lk];
                acce[f] = MFMA16(a, bb, acce[f], 0, 0, 0);
            }
        }
#pragma unroll
        for (int f = 0; f < 8; ++f) {
            float bias = be[e * 128 + 16 * f + lr];
#pragma unroll
            for (int i = 0; i < 4; ++i)
                macc[f][i] += rw[e][i] * silu_f(acce[f][i] + bias);
        }
    }
    // moe -> A3 (region disjoint from sA2/sWe; no barrier needed)
#pragma unroll
    for (int f = 0; f < 8; ++f) {
        int c = 16 * f + lr;
#pragma unroll
        for (int i = 0; i < 4; ++i)
            sA3[(mrow + i) * 136 + c] = f2bf(macc[f][i]);
    }

    // ============ GEMM3: silu(moe @ W3^T + b3) + x ============
#pragma unroll 1
    for (int h = 0; h < 2; ++h) {
        __syncthreads();                 // e3 readers of sWe done; A3 writes drain
#pragma unroll
        for (int i9 = 0; i9 < 9; ++i9)
            if (i9 * 256 + tid < 2176)
                dma_u16(wbf + (size_t)(143360 + h * 17408), sW3, i9, tid);
        __syncthreads();
        f32x4 acc3[8];
#pragma unroll
        for (int f = 0; f < 8; ++f) acc3[f] = (f32x4){0.f, 0.f, 0.f, 0.f};
#pragma unroll
        for (int ks = 0; ks < 4; ++ks) {
            short8 a = *(const short8*)&sA3[(16 * w + lr) * 136 + ks * 32 + lk];
#pragma unroll
            for (int f = 0; f < 8; ++f) {
                short8 bb = *(const short8*)&sW3[(16 * f + lr) * 136 + ks * 32 + lk];
                acc3[f] = MFMA16(a, bb, acc3[f], 0, 0, 0);
            }
        }
        __syncthreads();                 // sW3/sA3 readers done; sY may overwrite
#pragma unroll
        for (int f = 0; f < 8; ++f) {
            int o = 16 * f + lr;
            float bias = b3[h * 128 + o];
#pragma unroll
            for (int i = 0; i < 4; ++i)
                sY[o * 68 + mrow + i] = silu_f(acc3[f][i] + bias);
        }
        __syncthreads();
#pragma unroll
        for (int q = 0; q < 8; ++q) {    // coalesced residual-add + store
            int idx = q * 256 + tid;
            int o = idx >> 4, mq = (idx & 15) << 2;
            int og = h * 128 + o;
            float4 vy = *(float4*)&sY[o * 68 + mq];
            float4 r  = *(const float4*)&xb[(size_t)og * 4096 + mq];
            vy.x += r.x; vy.y += r.y; vy.z += r.z; vy.w += r.w;
            *(float4*)&ob[(size_t)og * 4096 + mq] = vy;
        }
    }
}

extern "C" void kernel_launch(void* const* d_in, const int* in_sizes, int n_in,
                              void* d_out, int out_size, void* d_ws, size_t ws_size,
                              hipStream_t stream)
{
    const float* x  = (const float*)d_in[0];
    const float* W1 = (const float*)d_in[1];
    const float* b1 = (const float*)d_in[2];
    const float* Wr = (const float*)d_in[3];
    const float* br = (const float*)d_in[4];
    const float* We = (const float*)d_in[5];
    const float* be = (const float*)d_in[6];
    const float* W3 = (const float*)d_in[7];
    const float* b3 = (const float*)d_in[8];
    float* outp = (float*)d_out;
    u16* wbf = (u16*)d_ws;

    hipLaunchKernelGGL(prep_weights, dim3(552), dim3(256), 0, stream,
                       W1, We, W3, wbf);
    hipLaunchKernelGGL(fused_moe_mfma, dim3(512), dim3(256), 0, stream,
                       x, b1, Wr, br, be, b3, wbf, outp);
}

// Round 11
// 54.305 us; speedup vs baseline: 2.8934x; 1.0657x over previous
//
#include <hip/hip_runtime.h>
#include <hip/hip_bf16.h>

// B=8, C1=256, HW=4096 (N=32768), Ch=128, C2=256, E=4, K=2
// ws layout (u16):
//   W1hi [kc=4][128][72] @0        (36864)
//   W1lo [kc=4][128][72] @36864    (36864)
//   Wec  [e=4][128][128] swz @73728  (65536)
//   W3c  [h=2][128][128] swz @139264 (32768)
// Chunk swizzle: logical 8-u16 group gi of row o stored at
//   ps = (gi&8) | ((gi ^ key(o)) & 7),  key(o) = (o ^ (o>>2)) & 7  (involution).

typedef unsigned short u16;
typedef unsigned int   u32;
typedef __attribute__((ext_vector_type(8))) short short8;
typedef __attribute__((ext_vector_type(4))) float f32x4;

#define MFMA16 __builtin_amdgcn_mfma_f32_16x16x32_bf16

__device__ __forceinline__ float silu_f(float v) { return v / (1.0f + __expf(-v)); }
__device__ __forceinline__ u16 f2bf(float f) {
    u32 u = __float_as_uint(f);
    return (u16)((u + 0x7fff + ((u >> 16) & 1)) >> 16);
}
__device__ __forceinline__ float bf2f(u16 h) { return __uint_as_float(((u32)h) << 16); }
__device__ __forceinline__ u32 pkbf(float a, float b) {
    __hip_bfloat162 h2 = __float22bfloat162_rn(make_float2(a, b));
    u32 r; __builtin_memcpy(&r, &h2, 4); return r;
}
__device__ __forceinline__ int swzkey(int row) { return (row ^ (row >> 2)) & 7; }

__global__ void prep_weights(const float* __restrict__ W1,
                             const float* __restrict__ We,
                             const float* __restrict__ W3,
                             u16* __restrict__ ws)
{
    int idx = blockIdx.x * 256 + threadIdx.x;
    if (idx < 36864) {                       // W1 hi+lo, K-chunks of 64, stride 72
        int kc = idx / 9216, r = idx % 9216;
        int n = r / 72, j = r % 72;
        float v = (j < 64) ? W1[n * 256 + kc * 64 + j] : 0.0f;
        u16 h = f2bf(v);
        float lo = v - bf2f(h);
        ws[idx] = h;
        ws[36864 + idx] = f2bf(lo);
    } else if (idx < 102400) {               // We center taps, [e][128][128] swz
        int i = idx - 36864;
        int e = i >> 14, r = i & 16383;
        int o = r >> 7, rem = r & 127;
        int ps = rem >> 3, t = rem & 7;
        int gi = (ps & 8) | ((ps ^ swzkey(o)) & 7);
        int c = gi * 8 + t;
        ws[73728 + i] = f2bf(We[(size_t)(((e * 128 + o) * 128 + c) * 9) + 4]);
    } else if (idx < 135168) {               // W3, [h][128][128] swz
        int i = idx - 102400;
        int h = i >> 14, r = i & 16383;
        int o = r >> 7, rem = r & 127;
        int ps = rem >> 3, t = rem & 7;
        int gi = (ps & 8) | ((ps ^ swzkey(o)) & 7);
        int c = gi * 8 + t;
        ws[139264 + i] = f2bf(W3[(size_t)(h * 128 + o) * 128 + c]);
    }
}

// Linear 16B-per-lane DMA for a 32 KB chunk (2048 units, uniform 8/thread).
__device__ __forceinline__ void stage_chunk(const u16* __restrict__ g, u16* l, int tid) {
#pragma unroll
    for (int i = 0; i < 8; ++i)
        __builtin_amdgcn_global_load_lds(g + (size_t)(i * 256 + tid) * 8,
                                         l + (size_t)(i * 256 + (tid & 192)) * 8, 16, 0, 0);
}
// Guarded variant used by P1 (1152 units).
__device__ __forceinline__ void dma_u16(const u16* __restrict__ g, u16* l, int i, int tid) {
    int idx = i * 256 + tid;
    int ub  = i * 256 + (tid & 192);
    __builtin_amdgcn_global_load_lds(g + (size_t)idx * 8, l + ub * 8, 16, 0, 0);
}

// One block = 64 consecutive pixels. 4 waves. Arithmetic bit-identical to the
// round-8 PASSING kernel; weight chunks now flow through a 2-buffer DMA chain
// (issue right after the freeing __syncthreads, drain at the next one).
__global__ __launch_bounds__(256, 2)
void fused_moe_mfma(const float* __restrict__ x,
                    const float* __restrict__ b1,
                    const float* __restrict__ Wrg,
                    const float* __restrict__ br,
                    const float* __restrict__ be,
                    const float* __restrict__ b3,
                    const u16* __restrict__ wbf,
                    float* __restrict__ out)
{
    __shared__ __align__(16) unsigned char smem[81920];
    // P1 regions (dead after P1):
    u16*   const sWhi = (u16*)(smem);             // [128][72] = 18432 B
    u16*   const sWlo = (u16*)(smem + 18432);
    u16*   const sAhi = (u16*)(smem + 36864);     // [64][72] = 9216 B
    u16*   const sAlo = (u16*)(smem + 46080);     // ends 55296
    // P2/P3 regions:
    u16*   const A2   = (u16*)(smem);             // [64][128] swz = 16384 B (A2, later A3)
    u16*   const bufA = (u16*)(smem + 16384);     // 32768 B
    u16*   const bufB = (u16*)(smem + 49152);     // 32768 B
    float* const sY   = (float*)(smem + 16384);   // [128][64] swz f32 (over bufA)

    const int tid = threadIdx.x;
    const int l  = tid & 63;
    const int w  = tid >> 6;
    const int lr = l & 15;
    const int g  = l >> 4;
    const int lk = g * 8;
    const int mrow = 16 * w + 4 * g;
    const int arow = 16 * w + lr;
    const int akey = swzkey(arow);
    int okey[8];
#pragma unroll
    for (int f = 0; f < 8; ++f) okey[f] = swzkey(16 * f + lr);

    const int n0  = blockIdx.x << 6;
    const float* xb = x   + ((size_t)(n0 >> 12) * 256) * 4096 + (n0 & 4095);
    float*       ob = out + ((size_t)(n0 >> 12) * 256) * 4096 + (n0 & 4095);

    // ============ P1: GEMM1, split-bf16 4-pass (identical to R8) ============
    f32x4 acc1[8];
#pragma unroll
    for (int f = 0; f < 8; ++f) acc1[f] = (f32x4){0.f, 0.f, 0.f, 0.f};

    const int c2a = tid >> 4;
    const int c2b = 16 + c2a;
    const int m4  = (tid & 15) << 2;

#pragma unroll 1
    for (int kc = 0; kc < 4; ++kc) {
        __syncthreads();
        const float* xa0 = xb + (size_t)(kc * 64 + 2 * c2a) * 4096 + m4;
        const float* xa1 = xb + (size_t)(kc * 64 + 2 * c2b) * 4096 + m4;
        float4 fa0 = *(const float4*)xa0;
        float4 fb0 = *(const float4*)(xa0 + 4096);
        float4 fa1 = *(const float4*)xa1;
        float4 fb1 = *(const float4*)(xa1 + 4096);
#pragma unroll
        for (int i = 0; i < 5; ++i) {
            if (i * 256 + tid < 1152) {
                dma_u16(wbf + (size_t)kc * 9216,           sWhi, i, tid);
                dma_u16(wbf + (size_t)(36864 + kc * 9216), sWlo, i, tid);
            }
        }
        u32* H = (u32*)sAhi; u32* L = (u32*)sAlo;
        {
            float fav[4] = {fa0.x, fa0.y, fa0.z, fa0.w};
            float fbv[4] = {fb0.x, fb0.y, fb0.z, fb0.w};
#pragma unroll
            for (int r = 0; r < 4; ++r) {
                int ui = (m4 + r) * 36 + c2a;
                u32 hi = pkbf(fav[r], fbv[r]);
                float la = fav[r] - __uint_as_float(hi << 16);
                float lb = fbv[r] - __uint_as_float(hi & 0xffff0000u);
                H[ui] = hi; L[ui] = pkbf(la, lb);
            }
        }
        {
            float fav[4] = {fa1.x, fa1.y, fa1.z, fa1.w};
            float fbv[4] = {fb1.x, fb1.y, fb1.z, fb1.w};
#pragma unroll
            for (int r = 0; r < 4; ++r) {
                int ui = (m4 + r) * 36 + c2b;
                u32 hi = pkbf(fav[r], fbv[r]);
                float la = fav[r] - __uint_as_float(hi << 16);
                float lb = fbv[r] - __uint_as_float(hi & 0xffff0000u);
                H[ui] = hi; L[ui] = pkbf(la, lb);
            }
        }
        __syncthreads();
#pragma unroll
        for (int ks = 0; ks < 2; ++ks) {
            short8 ah = *(const short8*)&sAhi[(16 * w + lr) * 72 + ks * 32 + lk];
            short8 al = *(const short8*)&sAlo[(16 * w + lr) * 72 + ks * 32 + lk];
#pragma unroll
            for (int f = 0; f < 8; ++f) {
                int bo = (16 * f + lr) * 72 + ks * 32 + lk;
                short8 bh = *(const short8*)&sWhi[bo];
                short8 bl = *(const short8*)&sWlo[bo];
                acc1[f] = MFMA16(ah, bh, acc1[f], 0, 0, 0);
                acc1[f] = MFMA16(al, bh, acc1[f], 0, 0, 0);
                acc1[f] = MFMA16(ah, bl, acc1[f], 0, 0, 0);
                acc1[f] = MFMA16(al, bl, acc1[f], 0, 0, 0);
            }
        }
    }
    __syncthreads();                     // P1 readers done; bufA/bufB now free

    // Chunks 0,1 (experts 0,1) fly under the whole epilogue.
    stage_chunk(wbf + 73728,         bufA, tid);
    stage_chunk(wbf + 73728 + 16384, bufB, tid);

    // ============ epilogue: xin fp32; A2 swz; fp32 router ============
    float xin[8][4];
#pragma unroll
    for (int f = 0; f < 8; ++f) {
        float bias = b1[16 * f + lr];
#pragma unroll
        for (int i = 0; i < 4; ++i) xin[f][i] = silu_f(acc1[f][i] + bias);
    }
#pragma unroll
    for (int f = 0; f < 8; ++f) {
        int c = 16 * f + lr, gi = c >> 3;
#pragma unroll
        for (int i = 0; i < 4; ++i) {
            int m = mrow + i;
            int ps = (gi & 8) | ((gi ^ swzkey(m)) & 7);
            A2[m * 128 + ps * 8 + (c & 7)] = f2bf(xin[f][i]);
        }
    }

    float lg[4][4];
#pragma unroll
    for (int e = 0; e < 4; ++e)
#pragma unroll
        for (int i = 0; i < 4; ++i) lg[e][i] = 0.f;
#pragma unroll
    for (int f = 0; f < 8; ++f) {
        int c = 16 * f + lr;
        float w0 = Wrg[c], w1 = Wrg[128 + c], w2 = Wrg[256 + c], w3 = Wrg[384 + c];
#pragma unroll
        for (int i = 0; i < 4; ++i) {
            float xv = xin[f][i];
            lg[0][i] += xv * w0; lg[1][i] += xv * w1;
            lg[2][i] += xv * w2; lg[3][i] += xv * w3;
        }
    }
#pragma unroll
    for (int d = 1; d < 16; d <<= 1)
#pragma unroll
        for (int e = 0; e < 4; ++e)
#pragma unroll
            for (int i = 0; i < 4; ++i)
                lg[e][i] += __shfl_xor(lg[e][i], d, 64);

    float br0 = br[0], br1 = br[1], br2 = br[2], br3 = br[3];
    float rw[4][4];
#pragma unroll
    for (int i = 0; i < 4; ++i) {
        float le0 = lg[0][i] + br0, le1 = lg[1][i] + br1;
        float le2 = lg[2][i] + br2, le3 = lg[3][i] + br3;
        int c0 = (le1 > le0) + (le2 > le0) + (le3 > le0);
        int c1 = (le0 >= le1) + (le2 > le1) + (le3 > le1);
        int c2 = (le0 >= le2) + (le1 >= le2) + (le3 > le2);
        int c3 = (le0 >= le3) + (le1 >= le3) + (le2 >= le3);
        float m = fmaxf(fmaxf(le0, le1), fmaxf(le2, le3));
        float p0 = (c0 < 2) ? __expf(le0 - m) : 0.f;
        float p1 = (c1 < 2) ? __expf(le1 - m) : 0.f;
        float p2 = (c2 < 2) ? __expf(le2 - m) : 0.f;
        float p3 = (c3 < 2) ? __expf(le3 - m) : 0.f;
        float inv = 1.0f / (p0 + p1 + p2 + p3);
        rw[0][i] = p0 * inv; rw[1][i] = p1 * inv;
        rw[2][i] = p2 * inv; rw[3][i] = p3 * inv;
    }
    __syncthreads();                     // drains chunks 0,1; A2 visible

    // ============ P2: experts 0..3 (chain: chunk e+2 staged as buf frees) ============
    f32x4 macc[8];
#pragma unroll
    for (int f = 0; f < 8; ++f) macc[f] = (f32x4){0.f, 0.f, 0.f, 0.f};

#pragma unroll 1
    for (int e = 0; e < 4; ++e) {
        const u16* Wb = (e & 1) ? bufB : bufA;
        f32x4 acce[8];
#pragma unroll
        for (int f = 0; f < 8; ++f) acce[f] = (f32x4){0.f, 0.f, 0.f, 0.f};
#pragma unroll
        for (int ks = 0; ks < 4; ++ks) {
            int gi = ks * 4 + g;
            int psA = (gi & 8) | ((gi ^ akey) & 7);
            short8 a = *(const short8*)&A2[arow * 128 + psA * 8];
#pragma unroll
            for (int f = 0; f < 8; ++f) {
                int psB = (gi & 8) | ((gi ^ okey[f]) & 7);
                short8 bb = *(const short8*)&Wb[(16 * f + lr) * 128 + psB * 8];
                acce[f] = MFMA16(a, bb, acce[f], 0, 0, 0);
            }
        }
#pragma unroll
        for (int f = 0; f < 8; ++f) {
            float bias = be[e * 128 + 16 * f + lr];
#pragma unroll
            for (int i = 0; i < 4; ++i)
                macc[f][i] += rw[e][i] * silu_f(acce[f][i] + bias);
        }
        __syncthreads();                 // all waves done reading Wb; drains chunk e+1
        // chunk e+2 (experts 2,3 then W3 h0) -> buffer just freed (= Wb)
        if (e < 2)      stage_chunk(wbf + 73728 + (e + 2) * 16384, (e & 1) ? bufB : bufA, tid);
        else if (e == 2) stage_chunk(wbf + 139264,                 bufA, tid);   // W3 h0
        else             /* e == 3: W3 h1 staged after A3 barrier */ ;
    }

    // moe -> A3 (reuses A2 buffer; all A2 readers passed the e=3 barrier)
#pragma unroll
    for (int f = 0; f < 8; ++f) {
        int c = 16 * f + lr, gi = c >> 3;
#pragma unroll
        for (int i = 0; i < 4; ++i) {
            int m = mrow + i;
            int ps = (gi & 8) | ((gi ^ swzkey(m)) & 7);
            A2[m * 128 + ps * 8 + (c & 7)] = f2bf(macc[f][i]);
        }
    }
    __syncthreads();                     // A3 visible; drains W3 h0 chunk
    stage_chunk(wbf + 139264 + 16384, bufB, tid);   // W3 h1 (bufB freed at e=3 barrier)

    // ============ P3: GEMM3 + residual ============
#pragma unroll 1
    for (int h = 0; h < 2; ++h) {
        const u16* Wb = h ? bufB : bufA;
        f32x4 acc3[8];
#pragma unroll
        for (int f = 0; f < 8; ++f) acc3[f] = (f32x4){0.f, 0.f, 0.f, 0.f};
#pragma unroll
        for (int ks = 0; ks < 4; ++ks) {
            int gi = ks * 4 + g;
            int psA = (gi & 8) | ((gi ^ akey) & 7);
            short8 a = *(const short8*)&A2[arow * 128 + psA * 8];
#pragma unroll
            for (int f = 0; f < 8; ++f) {
                int psB = (gi & 8) | ((gi ^ okey[f]) & 7);
                short8 bb = *(const short8*)&Wb[(16 * f + lr) * 128 + psB * 8];
                acc3[f] = MFMA16(a, bb, acc3[f], 0, 0, 0);
            }
        }
        __syncthreads();                 // h=0: Wb readers done (sY may overwrite bufA);
                                         //      also drains W3 h1 chunk
                                         // h=1: sY(h0) readers done
        int mg = mrow >> 2;              // = 4w + g
#pragma unroll
        for (int f = 0; f < 8; ++f) {
            int o = 16 * f + lr;
            float bias = b3[h * 128 + o];
            float4 v;
            v.x = silu_f(acc3[f][0] + bias);
            v.y = silu_f(acc3[f][1] + bias);
            v.z = silu_f(acc3[f][2] + bias);
            v.w = silu_f(acc3[f][3] + bias);
            *(float4*)&sY[o * 64 + ((mg ^ okey[f]) << 2)] = v;
        }
        __syncthreads();
#pragma unroll
        for (int q = 0; q < 8; ++q) {    // coalesced residual-add + store
            int idx = q * 256 + tid;
            int o = idx >> 4, mq = idx & 15;
            int og = h * 128 + o;
            float4 vy = *(const float4*)&sY[o * 64 + ((mq ^ swzkey(o)) << 2)];
            size_t goff = (size_t)og * 4096 + (mq << 2);
            float4 r = *(const float4*)&xb[goff];
            vy.x += r.x; vy.y += r.y; vy.z += r.z; vy.w += r.w;
            *(float4*)&ob[goff] = vy;
        }
        if (h == 0) __syncthreads();     // protect sY before h=1 overwrites
    }
}

extern "C" void kernel_launch(void* const* d_in, const int* in_sizes, int n_in,
                              void* d_out, int out_size, void* d_ws, size_t ws_size,
                              hipStream_t stream)
{
    const float* x  = (const float*)d_in[0];
    const float* W1 = (const float*)d_in[1];
    const float* b1 = (const float*)d_in[2];
    const float* Wr = (const float*)d_in[3];
    const float* br = (const float*)d_in[4];
    const float* We = (const float*)d_in[5];
    const float* be = (const float*)d_in[6];
    const float* W3 = (const float*)d_in[7];
    const float* b3 = (const float*)d_in[8];
    float* outp = (float*)d_out;
    u16* wbf = (u16*)d_ws;

    hipLaunchKernelGGL(prep_weights, dim3(528), dim3(256), 0, stream,
                       W1, We, W3, wbf);
    hipLaunchKernelGGL(fused_moe_mfma, dim3(512), dim3(256), 0, stream,
                       x, b1, Wr, br, be, b3, wbf, outp);
}